// Round 18
// baseline (84.950 us; speedup 1.0000x reference)
//
#include <hip/hip_runtime.h>
#include <math.h>

// SimpleVQ: B=32, H=1, L=4096, D=64, S=512
#define NB 32
#define NL 4096
#define ND 64
#define NS 512
#define NTOK (NB*NL)          // 131072

// output layout (flat f32, return order)
#define OFF_Q 0
#define OFF_Z (NTOK*ND)
#define OFF_LC (OFF_Z + NTOK)
#define OFF_E (OFF_LC + 1)

typedef __attribute__((ext_vector_type(8))) short short8;
typedef __attribute__((ext_vector_type(4))) float f32x4;
typedef unsigned int u32;
typedef unsigned short u16;
typedef unsigned long long u64;

#define QCODES 128            // codes per staged quarter
#define TOKS 128              // tokens per block
#define TPB 512               // 8 waves
#define SLOTS 12              // candidate slots per token
#define SLOTP 13              // padded stride
#define EPS_H 1e-3f           // >= 2x 3-pass bf16-split h-error bound
#define NBLK (NTOK / TOKS)    // 1024 blocks

// round-to-nearest-even f32 -> bf16 bits
__device__ __forceinline__ u32 f2bf_rne(float x) {
    u32 u = __float_as_uint(x);
    return (u + 0x7fffu + ((u >> 16) & 1u)) >> 16;
}

__device__ __forceinline__ void upd_key(u64& best, float dist, int code) {
    u32 u = __float_as_uint(dist);
    u ^= (u >> 31) ? 0xFFFFFFFFu : 0x80000000u;   // monotone f32 -> u32
    u64 k = ((u64)u << 32) | (u32)code;
    if (k < best) best = k;
}

// ---------------------------------------------------------------------------
// Kernel 1: codebook. cb f32 (linear), cc f32, PRE-SWIZZLED bf16 hi/lo
// (granule g stored at g ^ (code&7)) so a linear LDS copy is conflict-free.
// ---------------------------------------------------------------------------
__global__ void cb_kernel(float* __restrict__ cb, float* __restrict__ cc,
                          u16* __restrict__ cbh, u16* __restrict__ cbl) {
    int s = blockIdx.x;        // 0..511
    int d = threadIdx.x;       // 0..63
    int j = (d < 32) ? d : (d - 32);
    double e = -(double)(2 * j) / 64.0;
    double invlam = pow(100000.0, e);
    double pre = (double)s * invlam;
    float val = (float)((d < 32) ? sin(pre) : cos(pre));

    float sq = val * val;
    #pragma unroll
    for (int off = 32; off > 0; off >>= 1) sq += __shfl_xor(sq, off);
    float mean = sq * (1.0f / 64.0f);
    float scale = (1.0f / sqrtf(mean + 1e-6f)) * 0.35355339059327379f;
    float c = val * scale;
    cb[s * ND + d] = c;

    float c2 = c * c;
    #pragma unroll
    for (int off = 32; off > 0; off >>= 1) c2 += __shfl_xor(c2, off);
    if (d == 0) cc[s] = c2;

    u32 hb = f2bf_rne(c);
    float hf = __uint_as_float(hb << 16);
    u32 lb = f2bf_rne(c - hf);
    int g = d >> 3, ee = d & 7;
    int pos = s * 64 + (((g ^ (s & 7)) << 3) | ee);
    cbh[pos] = (u16)hb;
    cbl[pos] = (u16)lb;
}

// ---------------------------------------------------------------------------
// Kernel 2 (FUSED): per block: 128 tokens, 8 waves, ~37.5 KB LDS ->
// 4 blocks/CU (32 waves/CU, HW max). r17 minus the hval filter array
// (provably output-neutral: exact rescore over a candidate superset) and
// slots shrunk to u16. All selection math byte-identical to r17.
// ---------------------------------------------------------------------------
__launch_bounds__(TPB, 4)
__global__ void fused_kernel(const float* __restrict__ vecs,
                             const float* __restrict__ mask,
                             const float* __restrict__ cb,
                             const float* __restrict__ cc,
                             const u16* __restrict__ cbh,
                             const u16* __restrict__ cbl,
                             float* __restrict__ outq,
                             float* __restrict__ outz,
                             float* __restrict__ oute,
                             float* __restrict__ partial) {
    __shared__ u16 ldsH[QCODES * 64];           // 16 KB
    __shared__ u16 ldsL[QCODES * 64];           // 16 KB
    __shared__ u16 slots[TOKS * SLOTP];         // 3.3 KB
    __shared__ u32 cnt_l[TOKS];                 // 0.5 KB
    __shared__ int z_l[TOKS];                   // 0.5 KB
    __shared__ float wsum[TPB / 64];

    const int tid = threadIdx.x;
    const int grp = blockIdx.x;      // 0..1023
    const int w = tid >> 6;          // wave 0..7
    const int lane = tid & 63;
    const int c16 = lane & 15;
    const int h = lane >> 4;

    // ---- P0: stage quarter 0 + zero counters ----
    #pragma unroll
    for (int i = 0; i < 2; ++i) {
        int k = i * TPB + tid;       // 1024 short8 per array
        ((short8*)ldsH)[k] = ((const short8*)cbh)[k];
        ((short8*)ldsL)[k] = ((const short8*)cbl)[k];
    }
    if (tid < TOKS) cnt_l[tid] = 0;

    // ---- B fragments direct from global. ----
    // B[k][col]: col = c16 (token), k = kk*32 + h*8 + e
    const int trow = w * 16 + c16;   // this lane's token 0..127
    short8 bh[2], bl[2];
    {
        const float* vp = vecs + (size_t)(grp * TOKS + trow) * ND;
        #pragma unroll
        for (int kk = 0; kk < 2; ++kk) {
            const float4* pp = (const float4*)(vp + kk * 32 + h * 8);
            float4 t0 = pp[0], t1 = pp[1];
            float x[8] = {t0.x, t0.y, t0.z, t0.w, t1.x, t1.y, t1.z, t1.w};
            short8 H, L;
            #pragma unroll
            for (int e2 = 0; e2 < 8; ++e2) {
                u32 hb = f2bf_rne(x[e2]);
                float hf = __uint_as_float(hb << 16);
                u32 lb = f2bf_rne(x[e2] - hf);
                H[e2] = (short)hb; L[e2] = (short)lb;
            }
            bh[kk] = H; bl[kk] = L;
        }
    }
    __syncthreads();                 // barrier #1: quarter 0 + counters ready

    // ---- P1: quarters, register-prefetched staging ----
    for (int q = 0; q < 4; ++q) {
        // prefetch next quarter into regs; latency hides under this quarter's MFMA
        short8 gh[2], gl[2];
        if (q < 3) {
            const short8* sH = (const short8*)(cbh + (q + 1) * QCODES * 64);
            const short8* sL = (const short8*)(cbl + (q + 1) * QCODES * 64);
            #pragma unroll
            for (int i = 0; i < 2; ++i) {
                gh[i] = sH[i * TPB + tid];
                gl[i] = sL[i * TPB + tid];
            }
        }

        #pragma unroll
        for (int c = 0; c < 2; ++c) {             // two 64-code chunks
            f32x4 acc[4];
            #pragma unroll
            for (int mt = 0; mt < 4; ++mt) {
                int cr = q * QCODES + c * 64 + mt * 16 + h * 4;
                f32x4 ini;
                ini[0] = -0.5f * cc[cr + 0];
                ini[1] = -0.5f * cc[cr + 1];
                ini[2] = -0.5f * cc[cr + 2];
                ini[3] = -0.5f * cc[cr + 3];
                acc[mt] = ini;
            }
            #pragma unroll
            for (int mt = 0; mt < 4; ++mt) {
                int code_l = c * 64 + mt * 16 + c16;
                int sw = code_l & 7;
                short8 ah[2], al[2];
                #pragma unroll
                for (int kk = 0; kk < 2; ++kk) {
                    int off = code_l * 64 + (((kk * 4 + h) ^ sw) << 3);
                    ah[kk] = *(const short8*)(ldsH + off);
                    al[kk] = *(const short8*)(ldsL + off);
                }
                #pragma unroll
                for (int kk = 0; kk < 2; ++kk) {
                    acc[mt] = __builtin_amdgcn_mfma_f32_16x16x32_bf16(ah[kk], bh[kk], acc[mt], 0, 0, 0);
                    acc[mt] = __builtin_amdgcn_mfma_f32_16x16x32_bf16(ah[kk], bl[kk], acc[mt], 0, 0, 0);
                    acc[mt] = __builtin_amdgcn_mfma_f32_16x16x32_bf16(al[kk], bh[kk], acc[mt], 0, 0, 0);
                }
            }
            // epilogue: chunk-max per token, eps-rescan -> candidate append
            float m = acc[0][0];
            #pragma unroll
            for (int mt = 0; mt < 4; ++mt) {
                m = fmaxf(m, fmaxf(fmaxf(acc[mt][0], acc[mt][1]),
                                   fmaxf(acc[mt][2], acc[mt][3])));
            }
            m = fmaxf(m, __shfl_xor(m, 16));
            m = fmaxf(m, __shfl_xor(m, 32));
            float thr = m - EPS_H;
            #pragma unroll
            for (int mt = 0; mt < 4; ++mt) {
                #pragma unroll
                for (int r = 0; r < 4; ++r) {
                    float v = acc[mt][r];
                    if (v >= thr) {
                        u32 pos = atomicAdd(&cnt_l[trow], 1u);
                        if (pos < (u32)SLOTS)
                            slots[trow * SLOTP + pos] = (u16)(q * QCODES + c * 64 + mt * 16 + h * 4 + r);
                    }
                }
            }
        }

        // swap in the prefetched quarter: barriers sandwich only the ds_writes
        if (q < 3) {
            __syncthreads();          // all waves done reading current quarter
            #pragma unroll
            for (int i = 0; i < 2; ++i) {
                int k = i * TPB + tid;
                ((short8*)ldsH)[k] = gh[i];
                ((short8*)ldsL)[k] = gl[i];
            }
            __syncthreads();          // new quarter visible
        }
    }
    // NO barrier here: wave w wrote candidates only for tokens [w*16,(w+1)*16)
    // and rescans exactly those tokens below (tid>>2 >> 4 == tid>>6 == w).

    // ---- P2: exact rescore of ALL candidates, 4 threads/token ----
    const int p  = tid >> 2;          // token-local 0..127
    const int qs = tid & 3;
    const int tok = grp * TOKS + p;

    float4 vf[16];
    {
        const float4* vr = (const float4*)(vecs + (size_t)tok * ND);
        #pragma unroll
        for (int g = 0; g < 16; ++g) vf[g] = vr[g];
    }
    float vv;
    {
        float a0 = 0.f, a1 = 0.f, a2 = 0.f, a3 = 0.f;
        #pragma unroll
        for (int i = 0; i < 16; ++i) {
            a0 = fmaf(vf[i].x, vf[i].x, a0);
            a1 = fmaf(vf[i].y, vf[i].y, a1);
            a2 = fmaf(vf[i].z, vf[i].z, a2);
            a3 = fmaf(vf[i].w, vf[i].w, a3);
        }
        vv = (a0 + a1) + (a2 + a3);
    }

    u64 best = 0xFFFFFFFFFFFFFFFFull;
    u32 cntraw = cnt_l[p];
    if (cntraw > (u32)SLOTS) {
        // overflow fallback: exact full scan (deterministic trigger & result)
        for (int code = qs; code < NS; code += 4) {
            const float4* cs = (const float4*)(cb + (size_t)code * ND);
            float d0 = 0.f, d1 = 0.f, d2 = 0.f, d3 = 0.f;
            #pragma unroll
            for (int i2 = 0; i2 < 16; ++i2) {
                float4 cv = cs[i2];
                d0 = fmaf(cv.x, vf[i2].x, d0);
                d1 = fmaf(cv.y, vf[i2].y, d1);
                d2 = fmaf(cv.z, vf[i2].z, d2);
                d3 = fmaf(cv.w, vf[i2].w, d3);
            }
            float dot = (d0 + d1) + (d2 + d3);
            float dist = (vv - 2.0f * dot) + cc[code];
            upd_key(best, dist, code);
        }
    } else {
        for (u32 j2 = qs; j2 < cntraw; j2 += 4) {
            int code = (int)slots[p * SLOTP + j2];
            const float4* cs = (const float4*)(cb + (size_t)code * ND);
            float d0 = 0.f, d1 = 0.f, d2 = 0.f, d3 = 0.f;
            #pragma unroll
            for (int i2 = 0; i2 < 16; ++i2) {
                float4 cv = cs[i2];
                d0 = fmaf(cv.x, vf[i2].x, d0);
                d1 = fmaf(cv.y, vf[i2].y, d1);
                d2 = fmaf(cv.z, vf[i2].z, d2);
                d3 = fmaf(cv.w, vf[i2].w, d3);
            }
            float dot = (d0 + d1) + (d2 + d3);
            float dist = (vv - 2.0f * dot) + cc[code];
            upd_key(best, dist, code);
        }
    }
    {
        u64 o = __shfl_xor(best, 1); if (o < best) best = o;
        o = __shfl_xor(best, 2); if (o < best) best = o;
    }

    float contrib = 0.0f;
    if (qs == 0) {
        int zi = (int)(best & 0xFFFFFFFFu);
        u32 du = (u32)(best >> 32);
        du ^= (du >> 31) ? 0x80000000u : 0xFFFFFFFFu;
        float dmin = __uint_as_float(du);
        float err = fmaxf(dmin, 0.0f);
        outz[tok] = (float)zi;
        oute[tok] = err;
        z_l[p] = zi;
        contrib = mask[tok] * err;
    }
    #pragma unroll
    for (int off = 32; off > 0; off >>= 1) contrib += __shfl_xor(contrib, off);
    if (lane == 0) wsum[w] = contrib;
    __syncthreads();
    if (tid == 0) {
        float t = 0.f;
        #pragma unroll
        for (int i = 0; i < TPB / 64; ++i) t += wsum[i];
        partial[grp] = t;
    }

    // ---- P3: coalesced quantized gather-write ----
    const float4* cb4 = (const float4*)cb;
    float4* qo = (float4*)(outq + (size_t)grp * TOKS * ND);
    #pragma unroll
    for (int i = 0; i < 4; ++i) {
        int gidx = i * TPB + tid;      // 2048 f4
        int t2 = gidx >> 4;
        int sub = gidx & 15;
        qo[gidx] = cb4[(size_t)z_l[t2] * 16 + sub];
    }
}

// ---------------------------------------------------------------------------
// Kernel 3: sum 1024 partials; l_commit = sum / (B*L)
// ---------------------------------------------------------------------------
__global__ void fin_kernel(const float* __restrict__ partial, float* __restrict__ outl) {
    int t = threadIdx.x;                 // 1024
    float x = partial[t];
    #pragma unroll
    for (int off = 32; off > 0; off >>= 1) x += __shfl_xor(x, off);
    __shared__ float ws[16];
    if ((t & 63) == 0) ws[t >> 6] = x;
    __syncthreads();
    if (t == 0) {
        float s = 0.f;
        #pragma unroll
        for (int i = 0; i < 16; ++i) s += ws[i];
        outl[0] = s / (float)NTOK;
    }
}

extern "C" void kernel_launch(void* const* d_in, const int* in_sizes, int n_in,
                              void* d_out, int out_size, void* d_ws, size_t ws_size,
                              hipStream_t stream) {
    const float* vecs = (const float*)d_in[0];   // [B,1,L,D] f32
    const float* mask = (const float*)d_in[1];   // [B,L] f32

    float* out = (float*)d_out;
    float* outq = out + OFF_Q;
    float* outz = out + OFF_Z;
    float* outl = out + OFF_LC;
    float* oute = out + OFF_E;

    // ws layout (f32 offsets): cb 32768 | cc 512 | cbh 16384 | cbl 16384 | partial
    float* ws_f = (float*)d_ws;
    float* cb = ws_f;
    float* cc = ws_f + 32768;
    u16*  cbh = (u16*)(ws_f + 33280);
    u16*  cbl = (u16*)(ws_f + 49664);
    float* partial = ws_f + 66048;

    cb_kernel<<<NS, 64, 0, stream>>>(cb, cc, cbh, cbl);
    fused_kernel<<<NBLK, TPB, 0, stream>>>(vecs, mask, cb, cc, cbh, cbl,
                                           outq, outz, oute, partial);
    fin_kernel<<<1, 1024, 0, stream>>>(partial, outl);
}

// Round 19
// 65.609 us; speedup vs baseline: 1.2948x; 1.2948x over previous
//
#include <hip/hip_runtime.h>
#include <math.h>

// SimpleVQ: B=32, H=1, L=4096, D=64, S=512
#define NB 32
#define NL 4096
#define ND 64
#define NS 512
#define NTOK (NB*NL)          // 131072

// output layout (flat f32, return order)
#define OFF_Q 0
#define OFF_Z (NTOK*ND)
#define OFF_LC (OFF_Z + NTOK)
#define OFF_E (OFF_LC + 1)

typedef __attribute__((ext_vector_type(8))) short short8;
typedef __attribute__((ext_vector_type(4))) float f32x4;
typedef unsigned int u32;
typedef unsigned short u16;
typedef unsigned long long u64;

#define QCODES 128            // codes per staged quarter
#define TOKS 128              // tokens per block
#define TPB 512               // 8 waves
#define SLOTS 12              // candidate slots per token
#define SLOTP 13              // padded stride (odd -> conflict-free scans)
#define EPS_H 1e-3f           // >= 2x 3-pass bf16-split h-error bound
#define NBLK (NTOK / TOKS)    // 1024 blocks

// round-to-nearest-even f32 -> bf16 bits
__device__ __forceinline__ u32 f2bf_rne(float x) {
    u32 u = __float_as_uint(x);
    return (u + 0x7fffu + ((u >> 16) & 1u)) >> 16;
}

__device__ __forceinline__ void upd_key(u64& best, float dist, int code) {
    u32 u = __float_as_uint(dist);
    u ^= (u >> 31) ? 0xFFFFFFFFu : 0x80000000u;   // monotone f32 -> u32
    u64 k = ((u64)u << 32) | (u32)code;
    if (k < best) best = k;
}

// ---------------------------------------------------------------------------
// Kernel 1: codebook. cb f32 (linear), cc f32, PRE-SWIZZLED bf16 hi/lo
// (granule g stored at g ^ (code&7)) so a linear LDS copy is conflict-free.
// ---------------------------------------------------------------------------
__global__ void cb_kernel(float* __restrict__ cb, float* __restrict__ cc,
                          u16* __restrict__ cbh, u16* __restrict__ cbl) {
    int s = blockIdx.x;        // 0..511
    int d = threadIdx.x;       // 0..63
    int j = (d < 32) ? d : (d - 32);
    double e = -(double)(2 * j) / 64.0;
    double invlam = pow(100000.0, e);
    double pre = (double)s * invlam;
    float val = (float)((d < 32) ? sin(pre) : cos(pre));

    float sq = val * val;
    #pragma unroll
    for (int off = 32; off > 0; off >>= 1) sq += __shfl_xor(sq, off);
    float mean = sq * (1.0f / 64.0f);
    float scale = (1.0f / sqrtf(mean + 1e-6f)) * 0.35355339059327379f;
    float c = val * scale;
    cb[s * ND + d] = c;

    float c2 = c * c;
    #pragma unroll
    for (int off = 32; off > 0; off >>= 1) c2 += __shfl_xor(c2, off);
    if (d == 0) cc[s] = c2;

    u32 hb = f2bf_rne(c);
    float hf = __uint_as_float(hb << 16);
    u32 lb = f2bf_rne(c - hf);
    int g = d >> 3, ee = d & 7;
    int pos = s * 64 + (((g ^ (s & 7)) << 3) | ee);
    cbh[pos] = (u16)hb;
    cbl[pos] = (u16)lb;
}

// ---------------------------------------------------------------------------
// Kernel 2 (FUSED): per block: 128 tokens, 8 waves, ~47 KB LDS -> 3 blocks/CU
// (24 waves/CU). Best-measured configuration (r17, 65.9 us): no svec (vecs is
// L2/L3-resident -> B-frags and P2 reads direct from global), hval global-h
// filter KEPT (prunes exact rescore to ~2-3 candidates/token), wave-local
// candidate lists (no P1->P2 barrier), register-prefetched quarter staging.
// ---------------------------------------------------------------------------
__launch_bounds__(TPB, 3)
__global__ void fused_kernel(const float* __restrict__ vecs,
                             const float* __restrict__ mask,
                             const float* __restrict__ cb,
                             const float* __restrict__ cc,
                             const u16* __restrict__ cbh,
                             const u16* __restrict__ cbl,
                             float* __restrict__ outq,
                             float* __restrict__ outz,
                             float* __restrict__ oute,
                             float* __restrict__ partial) {
    __shared__ u16 ldsH[QCODES * 64];           // 16 KB
    __shared__ u16 ldsL[QCODES * 64];           // 16 KB
    __shared__ u32 slots[TOKS * SLOTP];         // 6.5 KB
    __shared__ float hval[TOKS * SLOTP];        // 6.5 KB
    __shared__ u32 cnt_l[TOKS];                 // 0.5 KB
    __shared__ int z_l[TOKS];                   // 0.5 KB
    __shared__ float wsum[TPB / 64];

    const int tid = threadIdx.x;
    const int grp = blockIdx.x;      // 0..1023
    const int w = tid >> 6;          // wave 0..7
    const int lane = tid & 63;
    const int c16 = lane & 15;
    const int h = lane >> 4;

    // ---- P0: stage quarter 0 + zero counters ----
    #pragma unroll
    for (int i = 0; i < 2; ++i) {
        int k = i * TPB + tid;       // 1024 short8 per array
        ((short8*)ldsH)[k] = ((const short8*)cbh)[k];
        ((short8*)ldsL)[k] = ((const short8*)cbl)[k];
    }
    if (tid < TOKS) cnt_l[tid] = 0;

    // ---- B fragments direct from global. ----
    // B[k][col]: col = c16 (token), k = kk*32 + h*8 + e
    const int trow = w * 16 + c16;   // this lane's token 0..127
    short8 bh[2], bl[2];
    {
        const float* vp = vecs + (size_t)(grp * TOKS + trow) * ND;
        #pragma unroll
        for (int kk = 0; kk < 2; ++kk) {
            const float4* pp = (const float4*)(vp + kk * 32 + h * 8);
            float4 t0 = pp[0], t1 = pp[1];
            float x[8] = {t0.x, t0.y, t0.z, t0.w, t1.x, t1.y, t1.z, t1.w};
            short8 H, L;
            #pragma unroll
            for (int e2 = 0; e2 < 8; ++e2) {
                u32 hb = f2bf_rne(x[e2]);
                float hf = __uint_as_float(hb << 16);
                u32 lb = f2bf_rne(x[e2] - hf);
                H[e2] = (short)hb; L[e2] = (short)lb;
            }
            bh[kk] = H; bl[kk] = L;
        }
    }
    __syncthreads();                 // barrier #1: quarter 0 + counters ready

    // ---- P1: quarters, register-prefetched staging ----
    for (int q = 0; q < 4; ++q) {
        // prefetch next quarter into regs; latency hides under this quarter's MFMA
        short8 gh[2], gl[2];
        if (q < 3) {
            const short8* sH = (const short8*)(cbh + (q + 1) * QCODES * 64);
            const short8* sL = (const short8*)(cbl + (q + 1) * QCODES * 64);
            #pragma unroll
            for (int i = 0; i < 2; ++i) {
                gh[i] = sH[i * TPB + tid];
                gl[i] = sL[i * TPB + tid];
            }
        }

        #pragma unroll
        for (int c = 0; c < 2; ++c) {             // two 64-code chunks
            f32x4 acc[4];
            #pragma unroll
            for (int mt = 0; mt < 4; ++mt) {
                int cr = q * QCODES + c * 64 + mt * 16 + h * 4;
                f32x4 ini;
                ini[0] = -0.5f * cc[cr + 0];
                ini[1] = -0.5f * cc[cr + 1];
                ini[2] = -0.5f * cc[cr + 2];
                ini[3] = -0.5f * cc[cr + 3];
                acc[mt] = ini;
            }
            #pragma unroll
            for (int mt = 0; mt < 4; ++mt) {
                int code_l = c * 64 + mt * 16 + c16;
                int sw = code_l & 7;
                short8 ah[2], al[2];
                #pragma unroll
                for (int kk = 0; kk < 2; ++kk) {
                    int off = code_l * 64 + (((kk * 4 + h) ^ sw) << 3);
                    ah[kk] = *(const short8*)(ldsH + off);
                    al[kk] = *(const short8*)(ldsL + off);
                }
                #pragma unroll
                for (int kk = 0; kk < 2; ++kk) {
                    acc[mt] = __builtin_amdgcn_mfma_f32_16x16x32_bf16(ah[kk], bh[kk], acc[mt], 0, 0, 0);
                    acc[mt] = __builtin_amdgcn_mfma_f32_16x16x32_bf16(ah[kk], bl[kk], acc[mt], 0, 0, 0);
                    acc[mt] = __builtin_amdgcn_mfma_f32_16x16x32_bf16(al[kk], bh[kk], acc[mt], 0, 0, 0);
                }
            }
            // epilogue: chunk-max per token, eps-rescan -> candidate append
            float m = acc[0][0];
            #pragma unroll
            for (int mt = 0; mt < 4; ++mt) {
                m = fmaxf(m, fmaxf(fmaxf(acc[mt][0], acc[mt][1]),
                                   fmaxf(acc[mt][2], acc[mt][3])));
            }
            m = fmaxf(m, __shfl_xor(m, 16));
            m = fmaxf(m, __shfl_xor(m, 32));
            float thr = m - EPS_H;
            #pragma unroll
            for (int mt = 0; mt < 4; ++mt) {
                #pragma unroll
                for (int r = 0; r < 4; ++r) {
                    float v = acc[mt][r];
                    if (v >= thr) {
                        u32 pos = atomicAdd(&cnt_l[trow], 1u);
                        if (pos < (u32)SLOTS) {
                            slots[trow * SLOTP + pos] = (u32)(q * QCODES + c * 64 + mt * 16 + h * 4 + r);
                            hval[trow * SLOTP + pos] = v;
                        }
                    }
                }
            }
        }

        // swap in the prefetched quarter: barriers sandwich only the ds_writes
        if (q < 3) {
            __syncthreads();          // all waves done reading current quarter
            #pragma unroll
            for (int i = 0; i < 2; ++i) {
                int k = i * TPB + tid;
                ((short8*)ldsH)[k] = gh[i];
                ((short8*)ldsL)[k] = gl[i];
            }
            __syncthreads();          // new quarter visible
        }
    }
    // NO barrier here: wave w wrote candidates only for tokens [w*16,(w+1)*16)
    // and rescans exactly those tokens below (tid>>2 >> 4 == tid>>6 == w).

    // ---- P2: exact rescore, 4 threads/token; vf direct from global ----
    const int p  = tid >> 2;          // token-local 0..127
    const int qs = tid & 3;
    const int tok = grp * TOKS + p;

    float4 vf[16];
    {
        const float4* vr = (const float4*)(vecs + (size_t)tok * ND);
        #pragma unroll
        for (int g = 0; g < 16; ++g) vf[g] = vr[g];
    }
    float vv;
    {
        float a0 = 0.f, a1 = 0.f, a2 = 0.f, a3 = 0.f;
        #pragma unroll
        for (int i = 0; i < 16; ++i) {
            a0 = fmaf(vf[i].x, vf[i].x, a0);
            a1 = fmaf(vf[i].y, vf[i].y, a1);
            a2 = fmaf(vf[i].z, vf[i].z, a2);
            a3 = fmaf(vf[i].w, vf[i].w, a3);
        }
        vv = (a0 + a1) + (a2 + a3);
    }

    u32 cnt = cnt_l[p]; if (cnt > (u32)SLOTS) cnt = (u32)SLOTS;
    float hm = -3.4e38f;
    for (u32 j2 = 0; j2 < cnt; ++j2) hm = fmaxf(hm, hval[p * SLOTP + j2]);
    float thr2 = hm - EPS_H;

    u64 best = 0xFFFFFFFFFFFFFFFFull;
    for (u32 j2 = qs; j2 < cnt; j2 += 4) {
        if (hval[p * SLOTP + j2] >= thr2) {
            int code = (int)slots[p * SLOTP + j2];
            const float4* cs = (const float4*)(cb + (size_t)code * ND);
            float d0 = 0.f, d1 = 0.f, d2 = 0.f, d3 = 0.f;
            #pragma unroll
            for (int i2 = 0; i2 < 16; ++i2) {
                float4 cv = cs[i2];
                d0 = fmaf(cv.x, vf[i2].x, d0);
                d1 = fmaf(cv.y, vf[i2].y, d1);
                d2 = fmaf(cv.z, vf[i2].z, d2);
                d3 = fmaf(cv.w, vf[i2].w, d3);
            }
            float dot = (d0 + d1) + (d2 + d3);
            float dist = (vv - 2.0f * dot) + cc[code];
            upd_key(best, dist, code);
        }
    }
    {
        u64 o = __shfl_xor(best, 1); if (o < best) best = o;
        o = __shfl_xor(best, 2); if (o < best) best = o;
    }

    float contrib = 0.0f;
    if (qs == 0) {
        int zi = (int)(best & 0xFFFFFFFFu);
        u32 du = (u32)(best >> 32);
        du ^= (du >> 31) ? 0x80000000u : 0xFFFFFFFFu;
        float dmin = __uint_as_float(du);
        float err = fmaxf(dmin, 0.0f);
        outz[tok] = (float)zi;
        oute[tok] = err;
        z_l[p] = zi;
        contrib = mask[tok] * err;
    }
    #pragma unroll
    for (int off = 32; off > 0; off >>= 1) contrib += __shfl_xor(contrib, off);
    if (lane == 0) wsum[w] = contrib;
    __syncthreads();
    if (tid == 0) {
        float t = 0.f;
        #pragma unroll
        for (int i = 0; i < TPB / 64; ++i) t += wsum[i];
        partial[grp] = t;
    }

    // ---- P3: coalesced quantized gather-write ----
    const float4* cb4 = (const float4*)cb;
    float4* qo = (float4*)(outq + (size_t)grp * TOKS * ND);
    #pragma unroll
    for (int i = 0; i < 4; ++i) {
        int gidx = i * TPB + tid;      // 2048 f4
        int t2 = gidx >> 4;
        int sub = gidx & 15;
        qo[gidx] = cb4[(size_t)z_l[t2] * 16 + sub];
    }
}

// ---------------------------------------------------------------------------
// Kernel 3: sum 1024 partials; l_commit = sum / (B*L)
// ---------------------------------------------------------------------------
__global__ void fin_kernel(const float* __restrict__ partial, float* __restrict__ outl) {
    int t = threadIdx.x;                 // 1024
    float x = partial[t];
    #pragma unroll
    for (int off = 32; off > 0; off >>= 1) x += __shfl_xor(x, off);
    __shared__ float ws[16];
    if ((t & 63) == 0) ws[t >> 6] = x;
    __syncthreads();
    if (t == 0) {
        float s = 0.f;
        #pragma unroll
        for (int i = 0; i < 16; ++i) s += ws[i];
        outl[0] = s / (float)NTOK;
    }
}

extern "C" void kernel_launch(void* const* d_in, const int* in_sizes, int n_in,
                              void* d_out, int out_size, void* d_ws, size_t ws_size,
                              hipStream_t stream) {
    const float* vecs = (const float*)d_in[0];   // [B,1,L,D] f32
    const float* mask = (const float*)d_in[1];   // [B,L] f32

    float* out = (float*)d_out;
    float* outq = out + OFF_Q;
    float* outz = out + OFF_Z;
    float* outl = out + OFF_LC;
    float* oute = out + OFF_E;

    // ws layout (f32 offsets): cb 32768 | cc 512 | cbh 16384 | cbl 16384 | partial
    float* ws_f = (float*)d_ws;
    float* cb = ws_f;
    float* cc = ws_f + 32768;
    u16*  cbh = (u16*)(ws_f + 33280);
    u16*  cbl = (u16*)(ws_f + 49664);
    float* partial = ws_f + 66048;

    cb_kernel<<<NS, 64, 0, stream>>>(cb, cc, cbh, cbl);
    fused_kernel<<<NBLK, TPB, 0, stream>>>(vecs, mask, cb, cc, cbh, cbl,
                                           outq, outz, oute, partial);
    fin_kernel<<<1, 1024, 0, stream>>>(partial, outl);
}